// Round 4
// baseline (468.921 us; speedup 1.0000x reference)
//
#include <hip/hip_runtime.h>

#define NODES 8192
#define H1 256
#define EMB 64
#define IN_SIZE (NODES + EMB)   // 8256
#define HID3 128
#define NPART 256               // blocks in gcn2 stage (32 rows each)

// ws layout (floats)
#define X_OFF    0                        // 8192  : diag
#define S_OFF    (X_OFF + NODES)          // 8192  : s = adj @ x
#define PART_OFF (S_OFF + NODES)          // 256*256 : partial t
#define LS_OFF   (PART_OFF + NPART*H1)    // 64    : log_softmax row
#define Y1_OFF   (LS_OFF + EMB)           // 256
#define Y3_OFF   (Y1_OFF + H1)            // 128
#define CNT_OFF  (Y3_OFF + HID3)          // 2 ints: last-block counters

__device__ __forceinline__ float waveReduceSum(float v) {
    #pragma unroll
    for (int off = 32; off > 0; off >>= 1) v += __shfl_down(v, off, 64);
    return v;
}

// K1: x[i] = state[i][i]; also zero the last-block counters (ws is re-poisoned
// to 0xAA before every timed launch, so this must happen every call).
__global__ __launch_bounds__(256) void k_diag(const float* __restrict__ state,
                                              float* __restrict__ x,
                                              int* __restrict__ cnt) {
    int i = blockIdx.x * 256 + threadIdx.x;
    x[i] = state[(size_t)i * NODES + i];
    if (blockIdx.x == 0 && threadIdx.x < 2) cnt[threadIdx.x] = 0;
}

// K2 (the streamer): s[i] = dot(state[i,:], x) - x[i]^2.  2 rows per block:
// doubles per-lane outstanding loads, halves x re-reads from L2.
__global__ __launch_bounds__(256) void k_row(const float* __restrict__ state,
                                             const float* __restrict__ x,
                                             float* __restrict__ s) {
    __shared__ float red[2][4];
    const int i0 = blockIdx.x * 2;
    const int tid = threadIdx.x;
    const float4* r0 = (const float4*)(state + (size_t)i0 * NODES);
    const float4* r1 = (const float4*)(state + (size_t)(i0 + 1) * NODES);
    const float4* x4 = (const float4*)x;

    float a0 = 0.f, a1 = 0.f;
    #pragma unroll
    for (int it = 0; it < NODES / 4 / 256; ++it) {   // 8 iterations, 16B/lane/row
        int j = tid + it * 256;
        float4 xv = x4[j];
        float4 v0 = r0[j];
        float4 v1 = r1[j];
        a0 += v0.x * xv.x + v0.y * xv.y + v0.z * xv.z + v0.w * xv.w;
        a1 += v1.x * xv.x + v1.y * xv.y + v1.z * xv.z + v1.w * xv.w;
    }
    a0 = waveReduceSum(a0);
    a1 = waveReduceSum(a1);
    if ((tid & 63) == 0) { red[0][tid >> 6] = a0; red[1][tid >> 6] = a1; }
    __syncthreads();
    if (tid < 2) {
        float xi = x[i0 + tid];
        s[i0 + tid] = red[tid][0] + red[tid][1] + red[tid][2] + red[tid][3] - xi * xi;
    }
}

// K3: part[b][j] = sum_{i in b's 32 rows} a_i * relu(s_i*w1[j]+b1[j]),
//     a_i = adj[start][i] (0 at i==start).  Last-arriving block reduces all
//     parts, applies gc2 (t @ gc2_w + b2), relu, log_softmax -> ls[64].
__global__ __launch_bounds__(256) void k_gcn2(const float* __restrict__ s,
                                              const float* __restrict__ state,
                                              const int* __restrict__ pstart,
                                              const float* __restrict__ w1,
                                              const float* __restrict__ b1,
                                              const float* __restrict__ w2,
                                              const float* __restrict__ b2,
                                              float* __restrict__ part,
                                              float* __restrict__ ls,
                                              int* __restrict__ cnt) {
    __shared__ float ls_s[32], ls_a[32];
    __shared__ int lastFlag;
    const int b = blockIdx.x, t = threadIdx.x;
    const int start = *pstart;
    if (t < 32) {
        int i = b * 32 + t;
        ls_s[t] = s[i];
        float a = state[(size_t)start * NODES + i];
        ls_a[t] = (i == start) ? 0.f : a;
    }
    __syncthreads();
    const float w = w1[t], bb = b1[t];
    float acc = 0.f;
    #pragma unroll
    for (int q = 0; q < 32; ++q)
        acc += ls_a[q] * fmaxf(ls_s[q] * w + bb, 0.f);
    part[b * H1 + t] = acc;

    __threadfence();                       // publish part before signaling
    if (t == 0) lastFlag = (atomicAdd(&cnt[0], 1) == NPART - 1);
    __syncthreads();
    if (!lastFlag) return;
    __threadfence();                       // acquire other blocks' parts

    __shared__ float ts[H1];
    float tacc = 0.f;
    #pragma unroll 8
    for (int bb2 = 0; bb2 < NPART; ++bb2) tacc += part[bb2 * H1 + t];
    ts[t] = tacc;
    __syncthreads();
    if (t < EMB) {
        float u = 0.f;
        #pragma unroll 8
        for (int j = 0; j < H1; ++j) u += ts[j] * w2[j * EMB + t];
        u = fmaxf(u + b2[t], 0.f);
        float mx = u;
        #pragma unroll
        for (int off = 32; off; off >>= 1) mx = fmaxf(mx, __shfl_xor(mx, off, 64));
        float e = expf(u - mx);
        float se = e;
        #pragma unroll
        for (int off = 32; off; off >>= 1) se += __shfl_xor(se, off, 64);
        ls[t] = (u - mx) - logf(se);
    }
}

// K4: fc1 (block o -> y1[o]); last-arriving block additionally runs fc2+fc3.
__global__ __launch_bounds__(256) void k_head(const float* __restrict__ state,
                                              const int* __restrict__ pstart,
                                              const float* __restrict__ ls,
                                              const float* __restrict__ w,
                                              const float* __restrict__ b,
                                              const float* __restrict__ w2_,
                                              const float* __restrict__ b2_,
                                              const float* __restrict__ w3_,
                                              const float* __restrict__ b3_,
                                              float* __restrict__ y1,
                                              float* __restrict__ y3,
                                              int* __restrict__ cnt) {
    __shared__ float red[4];
    __shared__ int lastFlag;
    const int o = blockIdx.x;
    const int t = threadIdx.x;
    const int start = *pstart;
    const float4* e4 = (const float4*)(state + (size_t)start * NODES);
    const float4* w4 = (const float4*)(w + (size_t)o * IN_SIZE);
    float acc = 0.f;
    #pragma unroll
    for (int it = 0; it < 8; ++it) {
        int j = t + it * 256;
        float4 a = e4[j], ww = w4[j];
        acc += a.x * ww.x + a.y * ww.y + a.z * ww.z + a.w * ww.w;
    }
    if (t < 64) acc += ls[t] * w[(size_t)o * IN_SIZE + NODES + t];
    acc = waveReduceSum(acc);
    if ((t & 63) == 0) red[t >> 6] = acc;
    __syncthreads();
    if (t == 0) y1[o] = fmaxf(red[0] + red[1] + red[2] + red[3] + b[o], 0.f);

    __threadfence();
    if (t == 0) lastFlag = (atomicAdd(&cnt[1], 1) == H1 - 1);
    __syncthreads();
    if (!lastFlag) return;
    __threadfence();

    __shared__ float ly[H1];
    __shared__ float ly2[H1];
    ly[t] = y1[t];
    __syncthreads();
    {
        const float4* wv = (const float4*)(w2_ + (size_t)t * H1);
        float a2 = 0.f;
        #pragma unroll
        for (int j = 0; j < 64; ++j) {
            float4 ww = wv[j];
            a2 += ww.x * ly[j*4] + ww.y * ly[j*4+1] + ww.z * ly[j*4+2] + ww.w * ly[j*4+3];
        }
        ly2[t] = fmaxf(a2 + b2_[t], 0.f);
    }
    __syncthreads();
    if (t < HID3) {
        const float4* wv = (const float4*)(w3_ + (size_t)t * H1);
        float a3 = 0.f;
        #pragma unroll
        for (int j = 0; j < 64; ++j) {
            float4 ww = wv[j];
            a3 += ww.x * ly2[j*4] + ww.y * ly2[j*4+1] + ww.z * ly2[j*4+2] + ww.w * ly2[j*4+3];
        }
        y3[t] = fmaxf(a3 + b3_[t], 0.f);
    }
}

// K5: out[o] = relu(dot(y3, fc4_w[o,:]) + b[o]); one wave per output
__global__ __launch_bounds__(256) void k_fc4(const float* __restrict__ y3,
                                             const float* __restrict__ w,
                                             const float* __restrict__ b,
                                             float* __restrict__ out) {
    __shared__ float ly[HID3];
    const int t = threadIdx.x;
    if (t < HID3) ly[t] = y3[t];
    __syncthreads();
    const int wave = t >> 6, lane = t & 63;
    const int o = blockIdx.x * 4 + wave;
    const float* wr = w + (size_t)o * HID3;
    float acc = wr[lane] * ly[lane] + wr[64 + lane] * ly[64 + lane];
    acc = waveReduceSum(acc);
    if (lane == 0) out[o] = fmaxf(acc + b[o], 0.f);
}

extern "C" void kernel_launch(void* const* d_in, const int* in_sizes, int n_in,
                              void* d_out, int out_size, void* d_ws, size_t ws_size,
                              hipStream_t stream) {
    const float* state = (const float*)d_in[0];
    const int*   pstart= (const int*)  d_in[1];
    const float* gc1_w = (const float*)d_in[2];
    const float* gc1_b = (const float*)d_in[3];
    const float* gc2_w = (const float*)d_in[4];
    const float* gc2_b = (const float*)d_in[5];
    const float* fc1_w = (const float*)d_in[6];
    const float* fc1_b = (const float*)d_in[7];
    const float* fc2_w = (const float*)d_in[8];
    const float* fc2_b = (const float*)d_in[9];
    const float* fc3_w = (const float*)d_in[10];
    const float* fc3_b = (const float*)d_in[11];
    const float* fc4_w = (const float*)d_in[12];
    const float* fc4_b = (const float*)d_in[13];
    float* ws = (float*)d_ws;
    float* x    = ws + X_OFF;
    float* s    = ws + S_OFF;
    float* part = ws + PART_OFF;
    float* ls   = ws + LS_OFF;
    float* y1   = ws + Y1_OFF;
    float* y3   = ws + Y3_OFF;
    int*   cnt  = (int*)(ws + CNT_OFF);
    float* out  = (float*)d_out;

    k_diag <<<NODES / 256, 256, 0, stream>>>(state, x, cnt);
    k_row  <<<NODES / 2,   256, 0, stream>>>(state, x, s);
    k_gcn2 <<<NPART,       256, 0, stream>>>(s, state, pstart, gc1_w, gc1_b,
                                             gc2_w, gc2_b, part, ls, cnt);
    k_head <<<H1,          256, 0, stream>>>(state, pstart, ls, fc1_w, fc1_b,
                                             fc2_w, fc2_b, fc3_w, fc3_b, y1, y3, cnt);
    k_fc4  <<<NODES / 4,   256, 0, stream>>>(y3, fc4_w, fc4_b, out);
}

// Round 5
// 434.969 us; speedup vs baseline: 1.0781x; 1.0781x over previous
//
#include <hip/hip_runtime.h>

#define NODES 8192
#define H1 256
#define EMB 64
#define IN_SIZE (NODES + EMB)   // 8256
#define HID3 128
#define NPART 256               // blocks in k_tpart (32 rows each)

// ws layout (floats)
#define X_OFF    0                        // 8192  : diag
#define S_OFF    (X_OFF + NODES)          // 8192  : s = adj @ x
#define PART_OFF (S_OFF + NODES)          // 256*256 : partial t
#define LS_OFF   (PART_OFF + NPART*H1)    // 64    : log_softmax row
#define Y1_OFF   (LS_OFF + EMB)           // 256
#define Y3_OFF   (Y1_OFF + H1)            // 128

__device__ __forceinline__ float waveReduceSum(float v) {
    #pragma unroll
    for (int off = 32; off > 0; off >>= 1) v += __shfl_down(v, off, 64);
    return v;
}

// K1: x[i] = state[i][i]
__global__ __launch_bounds__(256) void k_diag(const float* __restrict__ state,
                                              float* __restrict__ x) {
    int i = blockIdx.x * 256 + threadIdx.x;
    x[i] = state[(size_t)i * NODES + i];
}

// K2 (the streamer): s[i] = dot(state[i,:], x) - x[i]^2   (adj zeroes the diagonal)
__global__ __launch_bounds__(256) void k_row(const float* __restrict__ state,
                                             const float* __restrict__ x,
                                             float* __restrict__ s) {
    __shared__ float red[4];
    const int i = blockIdx.x;
    const int tid = threadIdx.x;
    const float4* row4 = (const float4*)(state + (size_t)i * NODES);
    const float4* x4   = (const float4*)x;

    float acc = 0.f;
    #pragma unroll
    for (int it = 0; it < NODES / 4 / 256; ++it) {   // 8 iterations, 16B/lane
        int j = tid + it * 256;
        float4 r = row4[j];
        float4 xv = x4[j];
        acc += r.x * xv.x + r.y * xv.y + r.z * xv.z + r.w * xv.w;
    }
    acc = waveReduceSum(acc);
    if ((tid & 63) == 0) red[tid >> 6] = acc;
    __syncthreads();
    if (tid == 0) {
        float xi = x[i];
        s[i] = red[0] + red[1] + red[2] + red[3] - xi * xi;
    }
}

// K3: part[b][j] = sum_{i in block b's 32 rows} a_i * relu(s_i*w1[j] + b1[j])
//     where a_i = adj[start][i]  (0 at i==start)
__global__ __launch_bounds__(256) void k_tpart(const float* __restrict__ s,
                                               const float* __restrict__ state,
                                               const int* __restrict__ pstart,
                                               const float* __restrict__ w1,
                                               const float* __restrict__ b1,
                                               float* __restrict__ part) {
    __shared__ float ls_s[32], ls_a[32];
    const int b = blockIdx.x, t = threadIdx.x;
    const int start = *pstart;
    if (t < 32) {
        int i = b * 32 + t;
        ls_s[t] = s[i];
        float a = state[(size_t)start * NODES + i];
        ls_a[t] = (i == start) ? 0.f : a;
    }
    __syncthreads();
    const float w = w1[t], bb = b1[t];
    float acc = 0.f;
    #pragma unroll
    for (int q = 0; q < 32; ++q)
        acc += ls_a[q] * fmaxf(ls_s[q] * w + bb, 0.f);
    part[b * H1 + t] = acc;
}

// K4: t[j] = sum_b part[b][j];  u = relu(t @ gc2_w + b2);  ls = log_softmax(u)
__global__ __launch_bounds__(256) void k_sm(const float* __restrict__ part,
                                            const float* __restrict__ w2,
                                            const float* __restrict__ b2,
                                            float* __restrict__ ls) {
    __shared__ float ts[H1];
    const int t = threadIdx.x;
    float acc = 0.f;
    #pragma unroll 8
    for (int b = 0; b < NPART; ++b) acc += part[b * H1 + t];
    ts[t] = acc;
    __syncthreads();
    if (t < EMB) {
        float u = 0.f;
        #pragma unroll 8
        for (int j = 0; j < H1; ++j) u += ts[j] * w2[j * EMB + t];
        u = fmaxf(u + b2[t], 0.f);
        float mx = u;
        #pragma unroll
        for (int off = 32; off; off >>= 1) mx = fmaxf(mx, __shfl_xor(mx, off, 64));
        float e = expf(u - mx);
        float se = e;
        #pragma unroll
        for (int off = 32; off; off >>= 1) se += __shfl_xor(se, off, 64);
        ls[t] = (u - mx) - logf(se);
    }
}

// K5: y1[o] = relu(dot(e, fc1_w[o,:]) + b[o]);  e = [state[start,:], ls]
__global__ __launch_bounds__(256) void k_fc1(const float* __restrict__ state,
                                             const int* __restrict__ pstart,
                                             const float* __restrict__ ls,
                                             const float* __restrict__ w,
                                             const float* __restrict__ b,
                                             float* __restrict__ y1) {
    __shared__ float red[4];
    const int o = blockIdx.x;
    const int t = threadIdx.x;
    const int start = *pstart;
    const float4* e4 = (const float4*)(state + (size_t)start * NODES);
    const float4* w4 = (const float4*)(w + (size_t)o * IN_SIZE);
    float acc = 0.f;
    #pragma unroll
    for (int it = 0; it < 8; ++it) {
        int j = t + it * 256;
        float4 a = e4[j], ww = w4[j];
        acc += a.x * ww.x + a.y * ww.y + a.z * ww.z + a.w * ww.w;
    }
    if (t < 64) acc += ls[t] * w[(size_t)o * IN_SIZE + NODES + t];
    acc = waveReduceSum(acc);
    if ((t & 63) == 0) red[t >> 6] = acc;
    __syncthreads();
    if (t == 0) y1[o] = fmaxf(red[0] + red[1] + red[2] + red[3] + b[o], 0.f);
}

// K6: y2 = relu(fc2_w @ y1 + b2); y3 = relu(fc3_w @ y2 + b3)   (one block)
__global__ __launch_bounds__(256) void k_fc23(const float* __restrict__ y1,
                                              const float* __restrict__ w2_,
                                              const float* __restrict__ b2_,
                                              const float* __restrict__ w3_,
                                              const float* __restrict__ b3_,
                                              float* __restrict__ y3) {
    __shared__ float ly[H1];
    __shared__ float ly2[H1];
    const int t = threadIdx.x;
    ly[t] = y1[t];
    __syncthreads();
    const float4* w4 = (const float4*)(w2_ + (size_t)t * H1);
    float acc = 0.f;
    #pragma unroll
    for (int j = 0; j < 64; ++j) {
        float4 ww = w4[j];
        acc += ww.x * ly[j*4] + ww.y * ly[j*4+1] + ww.z * ly[j*4+2] + ww.w * ly[j*4+3];
    }
    ly2[t] = fmaxf(acc + b2_[t], 0.f);
    __syncthreads();
    if (t < HID3) {
        const float4* w43 = (const float4*)(w3_ + (size_t)t * H1);
        float a3 = 0.f;
        #pragma unroll
        for (int j = 0; j < 64; ++j) {
            float4 ww = w43[j];
            a3 += ww.x * ly2[j*4] + ww.y * ly2[j*4+1] + ww.z * ly2[j*4+2] + ww.w * ly2[j*4+3];
        }
        y3[t] = fmaxf(a3 + b3_[t], 0.f);
    }
}

// K7: out[o] = relu(dot(y3, fc4_w[o,:]) + b[o]); one wave per output
__global__ __launch_bounds__(256) void k_fc4(const float* __restrict__ y3,
                                             const float* __restrict__ w,
                                             const float* __restrict__ b,
                                             float* __restrict__ out) {
    __shared__ float ly[HID3];
    const int t = threadIdx.x;
    if (t < HID3) ly[t] = y3[t];
    __syncthreads();
    const int wave = t >> 6, lane = t & 63;
    const int o = blockIdx.x * 4 + wave;
    const float* wr = w + (size_t)o * HID3;
    float acc = wr[lane] * ly[lane] + wr[64 + lane] * ly[64 + lane];
    acc = waveReduceSum(acc);
    if (lane == 0) out[o] = fmaxf(acc + b[o], 0.f);
}

extern "C" void kernel_launch(void* const* d_in, const int* in_sizes, int n_in,
                              void* d_out, int out_size, void* d_ws, size_t ws_size,
                              hipStream_t stream) {
    const float* state = (const float*)d_in[0];
    const int*   pstart= (const int*)  d_in[1];
    const float* gc1_w = (const float*)d_in[2];
    const float* gc1_b = (const float*)d_in[3];
    const float* gc2_w = (const float*)d_in[4];
    const float* gc2_b = (const float*)d_in[5];
    const float* fc1_w = (const float*)d_in[6];
    const float* fc1_b = (const float*)d_in[7];
    const float* fc2_w = (const float*)d_in[8];
    const float* fc2_b = (const float*)d_in[9];
    const float* fc3_w = (const float*)d_in[10];
    const float* fc3_b = (const float*)d_in[11];
    const float* fc4_w = (const float*)d_in[12];
    const float* fc4_b = (const float*)d_in[13];
    float* ws = (float*)d_ws;
    float* x    = ws + X_OFF;
    float* s    = ws + S_OFF;
    float* part = ws + PART_OFF;
    float* ls   = ws + LS_OFF;
    float* y1   = ws + Y1_OFF;
    float* y3   = ws + Y3_OFF;
    float* out  = (float*)d_out;

    k_diag <<<NODES / 256, 256, 0, stream>>>(state, x);
    k_row  <<<NODES,       256, 0, stream>>>(state, x, s);
    k_tpart<<<NPART,       256, 0, stream>>>(s, state, pstart, gc1_w, gc1_b, part);
    k_sm   <<<1,           256, 0, stream>>>(part, gc2_w, gc2_b, ls);
    k_fc1  <<<H1,          256, 0, stream>>>(state, pstart, ls, fc1_w, fc1_b, y1);
    k_fc23 <<<1,           256, 0, stream>>>(y1, fc2_w, fc2_b, fc3_w, fc3_b, y3);
    k_fc4  <<<8192 / 4,    256, 0, stream>>>(y3, fc4_w, fc4_b, out);
}